// Round 2
// baseline (234.182 us; speedup 1.0000x reference)
//
#include <hip/hip_runtime.h>

// PositionEncoder: out[b][s][0:512] = x[b][s][:], out[b][s][512:517] = enc(s)
// B=64, S=1024, D=512, H=W=32.  enc[k] = ((x>>(4-k))&1) & !((y>>(4-k))&1),
// y=s>>5, x=s&31  (verified absmax=0.0 in round 1).
//
// Round-2 design: LDS-staged restreaming so BOTH global sides are aligned
// float4 (round 1 had scalarized loads -> ~1.2-3.8 TB/s).
//  - block owns 8 rows; out chunk [r0*517, r0*517+4136) is 16B-aligned
//    because r0 % 4 == 0 and 4136 % 4 == 0.
//  - stage 1: coalesced float4 loads of x, dword-scatter into LDS laid out
//    exactly as the out chunk (r*517 + c); enc floats filled closed-form.
//    8-way LDS bank aliasing here costs ~15 us total, hidden under HBM.
//  - stage 2: aligned ds_read_b128 + coalesced global_store_dwordx4.

static constexpr unsigned kS       = 1024;
static constexpr unsigned kD       = 512;
static constexpr unsigned kDOut    = 517;
static constexpr unsigned kRPB     = 8;                  // rows per block
static constexpr unsigned kThreads = 256;
static constexpr unsigned kXF4     = kRPB * kD / 4;      // 1024 x-float4s per block
static constexpr unsigned kOF4     = kRPB * kDOut / 4;   // 1034 out-float4s per block

__global__ __launch_bounds__(kThreads) void pe_kernel(
    const float* __restrict__ x, float* __restrict__ out) {
  __shared__ __align__(16) float lds[kRPB * kDOut];      // 4136 floats = 16544 B
  const unsigned t  = threadIdx.x;
  const unsigned r0 = blockIdx.x * kRPB;                 // global row base

  // ---- stage 1: x chunk -> LDS (out-chunk layout) ----
  const float4* x4 = reinterpret_cast<const float4*>(x) + (size_t)r0 * (kD / 4);
#pragma unroll
  for (unsigned it = 0; it < kXF4 / kThreads; ++it) {
    const unsigned f = t + it * kThreads;                // 0..1023
    const unsigned r = f >> 7;                           // 128 float4 per row
    const unsigned c = (f & 127u) * 4u;
    const float4 v = x4[f];
    const unsigned l = r * kDOut + c;
    lds[l + 0] = v.x; lds[l + 1] = v.y; lds[l + 2] = v.z; lds[l + 3] = v.w;
  }
  // encodings: kRPB*5 = 40 values
  if (t < kRPB * 5u) {
    const unsigned r  = t / 5u, k = t - r * 5u;
    const unsigned s  = (r0 + r) & (kS - 1u);
    const unsigned xx = s & 31u, yy = s >> 5, sh = 4u - k;
    lds[r * kDOut + kD + k] =
        (float)(((xx >> sh) & 1u) & ((~(yy >> sh)) & 1u));
  }
  __syncthreads();

  // ---- stage 2: LDS -> out, both sides aligned float4 ----
  float4* o4 = reinterpret_cast<float4*>(out) + (size_t)r0 * kDOut / 4u;
  const float4* l4 = reinterpret_cast<const float4*>(lds);
  for (unsigned f = t; f < kOF4; f += kThreads) {        // 1034 iters
    o4[f] = l4[f];
  }
}

extern "C" void kernel_launch(void* const* d_in, const int* in_sizes, int n_in,
                              void* d_out, int out_size, void* d_ws,
                              size_t ws_size, hipStream_t stream) {
  const float* x = (const float*)d_in[0];
  float* out = (float*)d_out;
  // 65536 rows / 8 rows-per-block = 8192 blocks
  pe_kernel<<<dim3(8192), dim3(kThreads), 0, stream>>>(x, out);
}

// Round 3
// 225.759 us; speedup vs baseline: 1.0373x; 1.0373x over previous
//
#include <hip/hip_runtime.h>

// PositionEncoder: out[b][s][0:512] = x[b][s][:], out[b][s][512:517] = enc(s)
// B=64, S=1024, D=512, H=W=32.  enc[k] = ((x>>(4-k))&1) & !((y>>(4-k))&1),
// y=s>>5, x=s&31  (verified absmax=0.0 rounds 1-2).
//
// Round-3: round-2 LDS-staged structure (both global sides aligned 16B) plus
// nontemporal cache hints on the 134 MB read-once / 135 MB write-once streams
// to avoid L2 allocate/evict overhead. Native ext_vector float4 so the
// __builtin_nontemporal_* builtins apply.
//
// Evidence log: R1 (scalar-load stream) 233.7 us total, R2 (LDS staged)
// 234.2 us total -> kernel is not the dominant term of dur_us; this round
// discriminates whether ANY kernel-side change moves the needle.

typedef float f32x4 __attribute__((ext_vector_type(4)));

static constexpr unsigned kS       = 1024;
static constexpr unsigned kD       = 512;
static constexpr unsigned kDOut    = 517;
static constexpr unsigned kRPB     = 8;                  // rows per block
static constexpr unsigned kThreads = 256;
static constexpr unsigned kXF4     = kRPB * kD / 4;      // 1024 x-float4s/block
static constexpr unsigned kOF4     = kRPB * kDOut / 4;   // 1034 out-float4s/block

__global__ __launch_bounds__(kThreads) void pe_kernel(
    const float* __restrict__ x, float* __restrict__ out) {
  __shared__ __align__(16) float lds[kRPB * kDOut];      // 16544 B
  const unsigned t  = threadIdx.x;
  const unsigned r0 = blockIdx.x * kRPB;

  // ---- stage 1: x chunk -> LDS (out-chunk layout), nt vector loads ----
  const f32x4* x4 = reinterpret_cast<const f32x4*>(x) + (size_t)r0 * (kD / 4);
#pragma unroll
  for (unsigned it = 0; it < kXF4 / kThreads; ++it) {
    const unsigned f = t + it * kThreads;                // 0..1023
    const unsigned r = f >> 7;                           // 128 f4 per row
    const unsigned c = (f & 127u) * 4u;
    const f32x4 v = __builtin_nontemporal_load(&x4[f]);
    const unsigned l = r * kDOut + c;
    lds[l + 0] = v[0]; lds[l + 1] = v[1]; lds[l + 2] = v[2]; lds[l + 3] = v[3];
  }
  // encodings: kRPB*5 = 40 values, closed form
  if (t < kRPB * 5u) {
    const unsigned r  = t / 5u, k = t - r * 5u;
    const unsigned s  = (r0 + r) & (kS - 1u);
    const unsigned xx = s & 31u, yy = s >> 5, sh = 4u - k;
    lds[r * kDOut + kD + k] =
        (float)(((xx >> sh) & 1u) & ((~(yy >> sh)) & 1u));
  }
  __syncthreads();

  // ---- stage 2: LDS -> out, aligned b128 reads + nt coalesced stores ----
  f32x4* o4 = reinterpret_cast<f32x4*>(out) + (size_t)r0 * kDOut / 4u;
  const f32x4* l4 = reinterpret_cast<const f32x4*>(lds);
#pragma unroll
  for (unsigned it = 0; it < kOF4 / kThreads; ++it) {    // 4 full passes
    const unsigned f = t + it * kThreads;
    __builtin_nontemporal_store(l4[f], &o4[f]);
  }
  if (t < kOF4 - (kOF4 / kThreads) * kThreads) {         // 10 leftover f4s
    const unsigned f = t + (kOF4 / kThreads) * kThreads;
    __builtin_nontemporal_store(l4[f], &o4[f]);
  }
}

extern "C" void kernel_launch(void* const* d_in, const int* in_sizes, int n_in,
                              void* d_out, int out_size, void* d_ws,
                              size_t ws_size, hipStream_t stream) {
  const float* x = (const float*)d_in[0];
  float* out = (float*)d_out;
  // 65536 rows / 8 rows-per-block = 8192 blocks
  pe_kernel<<<dim3(8192), dim3(kThreads), 0, stream>>>(x, out);
}